// Round 9
// baseline (662.530 us; speedup 1.0000x reference)
//
#include <hip/hip_runtime.h>

#define HIDDEN 2048
#define HEADS 16
#define HD 128
#define RANK 1024
#define SEQ 4096

typedef __bf16 bf16_t;
typedef __bf16 bf16x8 __attribute__((ext_vector_type(8)));
typedef __bf16 bf16x4 __attribute__((ext_vector_type(4)));
typedef float f32x4 __attribute__((ext_vector_type(4)));

#define MFMA_BF16(a, b, c) __builtin_amdgcn_mfma_f32_16x16x32_bf16((a), (b), (c), 0, 0, 0)

// async global->LDS, 16B per lane; dst must be wave-uniform (lane scatters +L*16)
__device__ __forceinline__ void gload16(const bf16_t* g, bf16_t* l) {
  __builtin_amdgcn_global_load_lds(
      (const __attribute__((address_space(1))) unsigned int*)g,
      (__attribute__((address_space(3))) unsigned int*)l, 16, 0, 0);
}

// ---------------------------------------------------------------------------
// fused fp32 -> bf16 cast of x + all weights
// ---------------------------------------------------------------------------
struct CastSeg { const float* s; bf16_t* d; int n4; };
struct CastArgs { CastSeg seg[8]; };

__global__ __launch_bounds__(256) void cast_bf16_kernel(CastArgs a) {
  const int stride = gridDim.x * blockDim.x;
  const int tid0 = blockIdx.x * blockDim.x + threadIdx.x;
#pragma unroll
  for (int i = 0; i < 8; i++) {
    const float4* src = (const float4*)a.seg[i].s;
    bf16x4* dst = (bf16x4*)a.seg[i].d;
    const int n4 = a.seg[i].n4;
    for (int j = tid0; j < n4; j += stride) {
      float4 v = src[j];
      dst[j] = bf16x4{(bf16_t)v.x, (bf16_t)v.y, (bf16_t)v.z, (bf16_t)v.w};
    }
  }
}

// ---------------------------------------------------------------------------
// C[M,128*Nblk] = A @ W^T, bf16 MFMA, global_load_lds staging, XOR-swizzled LDS
// BK=64: two K=32 sub-steps per barrier pair — halves barrier/drain count vs
// BK=32. Staging swizzle cl = cp ^ (row&7) over 8 chunks/row; fragment read
// phys = (kk*4+quad) ^ (l15&7) (same involution; 2-way bank aliasing = free).
// T1 XCD chunk-swizzle on the flattened block id (all grids %8==0 -> bijective).
// OUT_MODE 0: bf16 out (third 0 scaled by s0)
// OUT_MODE 1: f32 out + bias
// OUT_MODE 2: bf16 out for thirds 0,1 (third 0 scaled); third 2 written
//             TRANSPOSED to Ct[col][row] (ld=SEQ).
// ---------------------------------------------------------------------------
template <int OUT_MODE>
__global__ __launch_bounds__(256) void gemm3(const bf16_t* __restrict__ A, int lda, int aOff,
                                             const bf16_t* __restrict__ W0,
                                             const bf16_t* __restrict__ W1,
                                             const bf16_t* __restrict__ W2,
                                             int nPerThird, int K,
                                             void* __restrict__ Cp, int ldc, size_t cOff,
                                             const float* __restrict__ bias, float s0,
                                             bf16_t* __restrict__ Ct) {
  __shared__ bf16_t As[128 * 64];
  __shared__ bf16_t Bs[128 * 64];
  const int tid = threadIdx.x, lane = tid & 63, wave = tid >> 6;
  const int wr = wave >> 1, wc = wave & 1, quad = lane >> 4, l15 = lane & 15;

  // XCD chunk swizzle (bijective; nwg % 8 == 0 for all launches here)
  const int gx = gridDim.x, nwg = gx * gridDim.y;
  const int orig = blockIdx.x + gx * blockIdx.y;
  const int wgid = (orig & 7) * (nwg >> 3) + (orig >> 3);
  const int bx = wgid % gx, by = wgid / gx;

  const int n0g = bx * 128;
  const int third = n0g / nPerThird;
  const int n0 = n0g - third * nPerThird;
  const bf16_t* W = third == 0 ? W0 : (third == 1 ? W1 : W2);
  const bf16_t* Ab = A + (size_t)third * aOff;
  const int m0 = by * 128;
  const float sc = (third == 0) ? s0 : 1.f;

  f32x4 acc[4][4];
#pragma unroll
  for (int i = 0; i < 4; i++)
#pragma unroll
    for (int j = 0; j < 4; j++) acc[i][j] = f32x4{0.f, 0.f, 0.f, 0.f};

  const int KT = K >> 6;
  for (int kt = 0; kt < KT; ++kt) {
#pragma unroll
    for (int i = 0; i < 4; i++) {
      int slot = (wave * 4 + i) * 64 + lane;
      int row = slot >> 3, cp = slot & 7;
      int cl = cp ^ (row & 7);
      gload16(Ab + (size_t)(m0 + row) * lda + kt * 64 + cl * 8, As + (size_t)(wave * 4 + i) * 512);
    }
#pragma unroll
    for (int i = 0; i < 4; i++) {
      int slot = (wave * 4 + i) * 64 + lane;
      int row = slot >> 3, cp = slot & 7;
      int cl = cp ^ (row & 7);
      gload16(W + (size_t)(n0 + row) * K + kt * 64 + cl * 8, Bs + (size_t)(wave * 4 + i) * 512);
    }
    __syncthreads();

#pragma unroll
    for (int kk = 0; kk < 2; kk++) {
      bf16x8 af[4], bfr[4];
#pragma unroll
      for (int mt = 0; mt < 4; mt++) {
        int row = wr * 64 + mt * 16 + l15;
        int phys = (kk * 4 + quad) ^ (l15 & 7);
        af[mt] = *reinterpret_cast<const bf16x8*>(As + row * 64 + phys * 8);
      }
#pragma unroll
      for (int nt = 0; nt < 4; nt++) {
        int row = wc * 64 + nt * 16 + l15;
        int phys = (kk * 4 + quad) ^ (l15 & 7);
        bfr[nt] = *reinterpret_cast<const bf16x8*>(Bs + row * 64 + phys * 8);
      }
#pragma unroll
      for (int mt = 0; mt < 4; mt++)
#pragma unroll
        for (int nt = 0; nt < 4; nt++) acc[mt][nt] = MFMA_BF16(af[mt], bfr[nt], acc[mt][nt]);
    }
    __syncthreads();
  }

  if constexpr (OUT_MODE == 2) {
    if (third == 2) {
#pragma unroll
      for (int nt = 0; nt < 4; nt++) {
        int col = n0 + wc * 64 + nt * 16 + l15;
#pragma unroll
        for (int mt = 0; mt < 4; mt++) {
          int rowb = m0 + wr * 64 + mt * 16 + quad * 4;
          bf16x4 tv = {(bf16_t)acc[mt][nt][0], (bf16_t)acc[mt][nt][1],
                       (bf16_t)acc[mt][nt][2], (bf16_t)acc[mt][nt][3]};
          *reinterpret_cast<bf16x4*>(Ct + (size_t)col * SEQ + rowb) = tv;
        }
      }
      return;
    }
  }

#pragma unroll
  for (int nt = 0; nt < 4; nt++) {
    int col = n0 + wc * 64 + nt * 16 + l15;
    float bv = 0.f;
    if constexpr (OUT_MODE == 1) bv = bias[col];
#pragma unroll
    for (int mt = 0; mt < 4; mt++) {
      int rowb = m0 + wr * 64 + mt * 16 + quad * 4;
#pragma unroll
      for (int r = 0; r < 4; r++) {
        float vx = acc[mt][nt][r];
        if constexpr (OUT_MODE == 1)
          ((float*)Cp + (size_t)third * cOff)[(size_t)(rowb + r) * ldc + col] = vx + bv;
        else
          ((bf16_t*)Cp + (size_t)third * cOff)[(size_t)(rowb + r) * ldc + col] = (bf16_t)(vx * sc);
      }
    }
  }
}

// ---------------------------------------------------------------------------
// Flash attention, S^T formulation, K=32 PV, software-pipelined, softmax in
// the QK^T MFMA shadow. 4 waves x 32 q (qt=2; r5: qt=1 doubles LDS traffic;
// r7: 8-wave blocks spill — 8 waves/CU is structural for this tile).
// Round-9: mv DOUBLE-BUFFER — loadMask(t+1) fills nmv while smGroup consumes
// mv = mask(t) (fixes the r6 mask off-by-one AND removes the in-burst
// s_waitcnt on fresh mask loads). Every memory op now has a full iteration
// of flight, so a plain __syncthreads() per iter costs ~nothing.
// body(t): barrier -> stage(t+2) -> loadMaskN(t+1) -> qkT_sm(t+1)[softmax(t)
// in MFMA shadow] -> pv(t) -> mv=nmv. V triple-buffered, K double-buffered:
// LDS 80 KiB, 2 blocks/CU. exp2 = raw v_exp_f32.
// Layout invariants (verified r2): QK^T A-rows permuted so P lands in the
// K=32 B-operand layout; Ks swizzle ^((row&3)|((row&8)>>1)); Vs ^(row&7);
// Q pre-scaled by 1/sqrt(128)*log2e at projection time.
// ---------------------------------------------------------------------------
__global__ __launch_bounds__(256, 2) void attn_kernel(const bf16_t* __restrict__ qb,
                                                      const bf16_t* __restrict__ kb,
                                                      const bf16_t* __restrict__ vtp,
                                                      const float* __restrict__ mask,
                                                      bf16_t* __restrict__ ao) {
  __shared__ bf16_t Ks[2][64 * 128];  // [sk][d], 8-elem chunks, ^((row&3)|((row&8)>>1))
  __shared__ bf16_t Vs[3][128 * 64];  // [d][sk], 8-elem chunks, ^(row&7)
  const int tid = threadIdx.x, lane = tid & 63, w = tid >> 6;
  const int quad = lane >> 4, l15 = lane & 15;
  const int head = blockIdx.x, q0 = blockIdx.y * 128;  // head-major dispatch
  const float LOG2E = 1.4426950408889634f;
  const int NT = SEQ / 64;

  // resident Q fragments (already scaled by 1/sqrt(128)*log2e):
  // lane holds Q[q = qt*16+l15][d = ks*32 + quad*8 + j]
  bf16x8 qf[2][4];
#pragma unroll
  for (int qt = 0; qt < 2; qt++)
#pragma unroll
    for (int ks = 0; ks < 4; ks++)
      qf[qt][ks] = *reinterpret_cast<const bf16x8*>(
          qb + (size_t)(q0 + w * 32 + qt * 16 + l15) * HIDDEN + head * HD + ks * 32 + quad * 8);

  // O^T accumulator: [dt][qt], C-layout col=q=l15, row=d=quad*4+r
  f32x4 O[8][2];
#pragma unroll
  for (int dt = 0; dt < 8; dt++)
#pragma unroll
    for (int qt = 0; qt < 2; qt++) O[dt][qt] = f32x4{0.f, 0.f, 0.f, 0.f};
  float lacc[2] = {0.f, 0.f};

  auto stageK = [&](int kt, int buf) {
#pragma unroll
    for (int i = 0; i < 4; i++) {
      int slot = (w * 4 + i) * 64 + lane;
      int row = slot >> 4, cp = slot & 15;
      int cl = cp ^ ((row & 3) | ((row & 8) >> 1));
      gload16(kb + (size_t)(kt * 64 + row) * HIDDEN + head * HD + cl * 8,
              &Ks[buf][(size_t)(w * 4 + i) * 512]);
    }
  };
  auto stageV = [&](int kt, int buf) {
#pragma unroll
    for (int i = 0; i < 4; i++) {
      int slot = (w * 4 + i) * 64 + lane;
      int row = slot >> 3, cp = slot & 7;
      int cl = cp ^ (row & 7);
      gload16(vtp + (size_t)(head * HD + row) * SEQ + kt * 64 + cl * 8,
              &Vs[buf][(size_t)(w * 4 + i) * 512]);
    }
  };

  // per-lane constants for the permuted A-row reads
  const int sK = (l15 & 3) | (((l15 >> 2) & 1) << 2);  // swizzle key = rowA's bits {0,1,3}
  const int rA0 = ((l15 >> 2) << 3) + (l15 & 3);       // A-row base (kp=0, sub=0)

  f32x4 mv[2][2][2];   // mask(t) — consumed by smGroup this iter
  f32x4 nmv[2][2][2];  // mask(t+1) — loaded this iter, published at iter end
  auto loadMaskTo = [&](int kt, f32x4 (&dst)[2][2][2]) {
#pragma unroll
    for (int kp = 0; kp < 2; kp++)
#pragma unroll
      for (int sub = 0; sub < 2; sub++)
#pragma unroll
        for (int qt = 0; qt < 2; qt++)
          dst[kp][sub][qt] = *reinterpret_cast<const f32x4*>(
              mask + (size_t)(q0 + w * 32 + qt * 16 + l15) * SEQ + kt * 64 + kp * 32 + quad * 8 +
              sub * 4);
  };

  f32x4 sacc[2][2][2];   // scores of tile t (consumed by softmax groups)
  bf16x8 pf[2][2];       // [kp][qt]: j=0..3 <- sub0, j=4..7 <- sub1

  // softmax group (kp,sub) of the CURRENT sacc/mv: fma+exp+cvt, pure VALU
  auto smGroup = [&](int kp, int sub) {
#pragma unroll
    for (int qt = 0; qt < 2; qt++) {
      f32x4 e;
#pragma unroll
      for (int r = 0; r < 4; r++)
        e[r] = __builtin_amdgcn_exp2f(sacc[kp][sub][qt][r] + mv[kp][sub][qt][r] * LOG2E);
      lacc[qt] += (e[0] + e[1]) + (e[2] + e[3]);
#pragma unroll
      for (int r = 0; r < 4; r++) pf[kp][qt][sub * 4 + r] = (bf16_t)e[r];
    }
  };

  // plain QK^T into sacc (prologue only)
  auto qkT = [&](int buf) {
#pragma unroll
    for (int kp = 0; kp < 2; kp++)
#pragma unroll
      for (int sub = 0; sub < 2; sub++)
#pragma unroll
        for (int qt = 0; qt < 2; qt++) sacc[kp][sub][qt] = f32x4{0.f, 0.f, 0.f, 0.f};
#pragma unroll
    for (int ks = 0; ks < 4; ks++) {
      int phys = (ks * 4 + quad) ^ sK;
#pragma unroll
      for (int kp = 0; kp < 2; kp++)
#pragma unroll
        for (int sub = 0; sub < 2; sub++) {
          int rowA = kp * 32 + sub * 4 + rA0;
          bf16x8 ak = *reinterpret_cast<const bf16x8*>(&Ks[buf][rowA * 128 + phys * 8]);
#pragma unroll
          for (int qt = 0; qt < 2; qt++)
            sacc[kp][sub][qt] = MFMA_BF16(ak, qf[qt][ks], sacc[kp][sub][qt]);
        }
    }
  };

  // QK^T(t+1) into fresh regs, softmax(t) interleaved per ks-step; publish.
  auto qkT_sm = [&](int buf) {
    f32x4 ns[2][2][2];
#pragma unroll
    for (int kp = 0; kp < 2; kp++)
#pragma unroll
      for (int sub = 0; sub < 2; sub++)
#pragma unroll
        for (int qt = 0; qt < 2; qt++) ns[kp][sub][qt] = f32x4{0.f, 0.f, 0.f, 0.f};
#pragma unroll
    for (int ks = 0; ks < 4; ks++) {
      int phys = (ks * 4 + quad) ^ sK;
#pragma unroll
      for (int kp = 0; kp < 2; kp++)
#pragma unroll
        for (int sub = 0; sub < 2; sub++) {
          int rowA = kp * 32 + sub * 4 + rA0;
          bf16x8 ak = *reinterpret_cast<const bf16x8*>(&Ks[buf][rowA * 128 + phys * 8]);
#pragma unroll
          for (int qt = 0; qt < 2; qt++)
            ns[kp][sub][qt] = MFMA_BF16(ak, qf[qt][ks], ns[kp][sub][qt]);
        }
      smGroup(ks >> 1, ks & 1);  // VALU of tile t hides under the MFMA burst
    }
#pragma unroll
    for (int kp = 0; kp < 2; kp++)
#pragma unroll
      for (int sub = 0; sub < 2; sub++)
#pragma unroll
        for (int qt = 0; qt < 2; qt++) sacc[kp][sub][qt] = ns[kp][sub][qt];
  };

  auto pv = [&](const bf16_t* Vb) {
#pragma unroll
    for (int kp = 0; kp < 2; kp++)
#pragma unroll
      for (int dt = 0; dt < 8; dt++) {
        int row = dt * 16 + l15;
        int phys = (kp * 4 + quad) ^ (l15 & 7);
        bf16x8 av = *reinterpret_cast<const bf16x8*>(&Vb[row * 64 + phys * 8]);
#pragma unroll
        for (int qt = 0; qt < 2; qt++) O[dt][qt] = MFMA_BF16(av, pf[kp][qt], O[dt][qt]);
      }
  };

  // prologue: tiles 0 and 1 staged; sacc(0), mv(0) ready
  stageK(0, 0);
  stageV(0, 0);
  stageK(1, 1);
  stageV(1, 1);
  loadMaskTo(0, mv);
  __syncthreads();  // full drain once (prologue only)
  qkT(0);           // sacc(0)

  int vb_pv = 0;  // Vs buffer holding V(t)
  int vb_st = 2;  // Vs buffer receiving V(t+2)
  for (int t = 0; t < NT - 1; ++t) {
    __syncthreads();        // stages(t+1) had a full iter of flight -> ~free
    stageK(t + 2, t & 1);   // overwrites K(t) buffer — reads done pre-barrier
    stageV(t + 2, vb_st);   // overwrites V(t-1) buffer — reads done pre-barrier
    loadMaskTo(t + 1, nmv); // consumed NEXT iter — full iter of flight
    __builtin_amdgcn_s_setprio(1);
    qkT_sm((t + 1) & 1);    // sacc(t+1) MFMAs + softmax(t) [mv = mask(t)] interleaved
    pv(&Vs[vb_pv][0]);      // O += V(t)·P(t) — one unbroken 64-MFMA burst
    __builtin_amdgcn_s_setprio(0);
    // publish mask(t+1) for next iter's smGroups
#pragma unroll
    for (int kp = 0; kp < 2; kp++)
#pragma unroll
      for (int sub = 0; sub < 2; sub++)
#pragma unroll
        for (int qt = 0; qt < 2; qt++) mv[kp][sub][qt] = nmv[kp][sub][qt];
    vb_pv = vb_pv == 2 ? 0 : vb_pv + 1;
    vb_st = vb_st == 2 ? 0 : vb_st + 1;
  }
  // tail: t = NT-1 (mv = mask(NT-1); V(NT-1) resident in Vs[vb_pv])
  smGroup(0, 0);
  smGroup(0, 1);
  smGroup(1, 0);
  smGroup(1, 1);
  pv(&Vs[vb_pv][0]);

  // epilogue: reduce l across quads (lanes l15, +16, +32, +48 share q), write O
#pragma unroll
  for (int qt = 0; qt < 2; qt++) {
    float l = lacc[qt];
    l += __shfl_xor(l, 16, 64);
    l += __shfl_xor(l, 32, 64);
    lacc[qt] = 1.f / l;
  }
#pragma unroll
  for (int dt = 0; dt < 8; dt++)
#pragma unroll
    for (int qt = 0; qt < 2; qt++) {
      int q = q0 + w * 32 + qt * 16 + l15;
      int d = head * HD + dt * 16 + quad * 4;
      f32x4 o = O[dt][qt];
      bf16x4 ov = {(bf16_t)(o[0] * lacc[qt]), (bf16_t)(o[1] * lacc[qt]),
                   (bf16_t)(o[2] * lacc[qt]), (bf16_t)(o[3] * lacc[qt])};
      *reinterpret_cast<bf16x4*>(ao + (size_t)q * HIDDEN + d) = ov;
    }
}

// ---------------------------------------------------------------------------
extern "C" void kernel_launch(void* const* d_in, const int* in_sizes, int n_in,
                              void* d_out, int out_size, void* d_ws, size_t ws_size,
                              hipStream_t stream) {
  (void)in_sizes; (void)n_in; (void)out_size; (void)ws_size;
  const float* x = (const float*)d_in[0];
  const float* mask = (const float*)d_in[1];
  const float* qV = (const float*)d_in[2];
  const float* qU = (const float*)d_in[3];
  const float* kV = (const float*)d_in[4];
  const float* kU = (const float*)d_in[5];
  const float* vV = (const float*)d_in[6];
  const float* vU = (const float*)d_in[7];
  const float* oW = (const float*)d_in[8];
  const float* ob = (const float*)d_in[9];
  float* out = (float*)d_out;

  char* ws = (char*)d_ws;
  const size_t MB = 1ull << 20;
  bf16_t* xb  = (bf16_t*)(ws);            // 16 MiB [4096][2048]; reused as ao
  bf16_t* tmp = (bf16_t*)(ws + 16 * MB);  // 24 MiB [4096][3072]
  bf16_t* qkv = (bf16_t*)(ws + 40 * MB);  // 48 MiB: q, k sections + vt in v-section
  bf16_t* qVb = (bf16_t*)(ws + 88 * MB);
  bf16_t* qUb = (bf16_t*)(ws + 92 * MB);
  bf16_t* kVb = (bf16_t*)(ws + 96 * MB);
  bf16_t* kUb = (bf16_t*)(ws + 100 * MB);
  bf16_t* vVb = (bf16_t*)(ws + 104 * MB);
  bf16_t* vUb = (bf16_t*)(ws + 108 * MB);
  bf16_t* oWb = (bf16_t*)(ws + 112 * MB);  // ends at 120 MiB
  bf16_t* vt = qkv + 2 * (size_t)SEQ * HIDDEN;  // [2048][4096], written transposed by gemm3<2>

  // 1/sqrt(HD) * log2(e), folded into Q at the U-projection epilogue
  const float kQScale = 0.088388347648318447f * 1.4426950408889634f;

  CastArgs ca;
  ca.seg[0] = {x, xb, SEQ * HIDDEN / 4};
  ca.seg[1] = {qV, qVb, RANK * HIDDEN / 4};
  ca.seg[2] = {qU, qUb, HIDDEN * RANK / 4};
  ca.seg[3] = {kV, kVb, RANK * HIDDEN / 4};
  ca.seg[4] = {kU, kUb, HIDDEN * RANK / 4};
  ca.seg[5] = {vV, vVb, RANK * HIDDEN / 4};
  ca.seg[6] = {vU, vUb, HIDDEN * RANK / 4};
  ca.seg[7] = {oW, oWb, HIDDEN * HIDDEN / 4};
  cast_bf16_kernel<<<2048, 256, 0, stream>>>(ca);

  // fused V-projections: tmp[4096][3072] = xb @ {qV,kV,vV}^T
  gemm3<0><<<dim3(24, 32), 256, 0, stream>>>(xb, HIDDEN, 0, qVb, kVb, vVb, RANK, HIDDEN,
                                             tmp, 3 * RANK, (size_t)RANK, nullptr, 1.f, nullptr);
  // fused U-projections: q,k -> qkv sections (q pre-scaled); v -> vt TRANSPOSED
  gemm3<2><<<dim3(48, 32), 256, 0, stream>>>(tmp, 3 * RANK, RANK, qUb, kUb, vUb, HIDDEN, RANK,
                                             qkv, HIDDEN, (size_t)SEQ * HIDDEN, nullptr,
                                             kQScale, vt);
  // attention -> ao (= xb region); head-major grid, 4 waves x 32 q
  attn_kernel<<<dim3(HEADS, SEQ / 128), 256, 0, stream>>>(qkv, qkv + (size_t)SEQ * HIDDEN, vt,
                                                          mask, xb);
  // out = ao @ oW^T + b (fp32)
  gemm3<1><<<dim3(16, 32), 256, 0, stream>>>(xb, HIDDEN, 0, oWb, oWb, oWb, HIDDEN, HIDDEN,
                                             out, HIDDEN, 0, ob, 1.f, nullptr);
}

// Round 10
// 530.500 us; speedup vs baseline: 1.2489x; 1.2489x over previous
//
#include <hip/hip_runtime.h>

#define HIDDEN 2048
#define HEADS 16
#define HD 128
#define RANK 1024
#define SEQ 4096

typedef __bf16 bf16_t;
typedef __bf16 bf16x8 __attribute__((ext_vector_type(8)));
typedef __bf16 bf16x4 __attribute__((ext_vector_type(4)));
typedef float f32x4 __attribute__((ext_vector_type(4)));

#define MFMA_BF16(a, b, c) __builtin_amdgcn_mfma_f32_16x16x32_bf16((a), (b), (c), 0, 0, 0)

// async global->LDS, 16B per lane; dst must be wave-uniform (lane scatters +L*16)
__device__ __forceinline__ void gload16(const bf16_t* g, bf16_t* l) {
  __builtin_amdgcn_global_load_lds(
      (const __attribute__((address_space(1))) unsigned int*)g,
      (__attribute__((address_space(3))) unsigned int*)l, 16, 0, 0);
}

// ---------------------------------------------------------------------------
// fused fp32 -> bf16 cast of x + all weights
// ---------------------------------------------------------------------------
struct CastSeg { const float* s; bf16_t* d; int n4; };
struct CastArgs { CastSeg seg[8]; };

__global__ __launch_bounds__(256) void cast_bf16_kernel(CastArgs a) {
  const int stride = gridDim.x * blockDim.x;
  const int tid0 = blockIdx.x * blockDim.x + threadIdx.x;
#pragma unroll
  for (int i = 0; i < 8; i++) {
    const float4* src = (const float4*)a.seg[i].s;
    bf16x4* dst = (bf16x4*)a.seg[i].d;
    const int n4 = a.seg[i].n4;
    for (int j = tid0; j < n4; j += stride) {
      float4 v = src[j];
      dst[j] = bf16x4{(bf16_t)v.x, (bf16_t)v.y, (bf16_t)v.z, (bf16_t)v.w};
    }
  }
}

// ---------------------------------------------------------------------------
// C[M,128*Nblk] = A @ W^T, bf16 MFMA, global_load_lds staging, XOR-swizzled LDS
// BK=64 (r9-measured: −30 µs vs BK=32): two K=32 sub-steps per barrier pair.
// Staging swizzle cl = cp ^ (row&7); fragment read phys = (kk*4+quad)^(l15&7).
// T1 XCD chunk-swizzle on the flattened block id (all grids %8==0 -> bijective).
// OUT_MODE 0: bf16 out (third 0 scaled by s0)
// OUT_MODE 1: f32 out + bias
// OUT_MODE 2: bf16 out for thirds 0,1 (third 0 scaled); third 2 written
//             TRANSPOSED to Ct[col][row] (ld=SEQ).
// ---------------------------------------------------------------------------
template <int OUT_MODE>
__global__ __launch_bounds__(256) void gemm3(const bf16_t* __restrict__ A, int lda, int aOff,
                                             const bf16_t* __restrict__ W0,
                                             const bf16_t* __restrict__ W1,
                                             const bf16_t* __restrict__ W2,
                                             int nPerThird, int K,
                                             void* __restrict__ Cp, int ldc, size_t cOff,
                                             const float* __restrict__ bias, float s0,
                                             bf16_t* __restrict__ Ct) {
  __shared__ bf16_t As[128 * 64];
  __shared__ bf16_t Bs[128 * 64];
  const int tid = threadIdx.x, lane = tid & 63, wave = tid >> 6;
  const int wr = wave >> 1, wc = wave & 1, quad = lane >> 4, l15 = lane & 15;

  // XCD chunk swizzle (bijective; nwg % 8 == 0 for all launches here)
  const int gx = gridDim.x, nwg = gx * gridDim.y;
  const int orig = blockIdx.x + gx * blockIdx.y;
  const int wgid = (orig & 7) * (nwg >> 3) + (orig >> 3);
  const int bx = wgid % gx, by = wgid / gx;

  const int n0g = bx * 128;
  const int third = n0g / nPerThird;
  const int n0 = n0g - third * nPerThird;
  const bf16_t* W = third == 0 ? W0 : (third == 1 ? W1 : W2);
  const bf16_t* Ab = A + (size_t)third * aOff;
  const int m0 = by * 128;
  const float sc = (third == 0) ? s0 : 1.f;

  f32x4 acc[4][4];
#pragma unroll
  for (int i = 0; i < 4; i++)
#pragma unroll
    for (int j = 0; j < 4; j++) acc[i][j] = f32x4{0.f, 0.f, 0.f, 0.f};

  const int KT = K >> 6;
  for (int kt = 0; kt < KT; ++kt) {
#pragma unroll
    for (int i = 0; i < 4; i++) {
      int slot = (wave * 4 + i) * 64 + lane;
      int row = slot >> 3, cp = slot & 7;
      int cl = cp ^ (row & 7);
      gload16(Ab + (size_t)(m0 + row) * lda + kt * 64 + cl * 8, As + (size_t)(wave * 4 + i) * 512);
    }
#pragma unroll
    for (int i = 0; i < 4; i++) {
      int slot = (wave * 4 + i) * 64 + lane;
      int row = slot >> 3, cp = slot & 7;
      int cl = cp ^ (row & 7);
      gload16(W + (size_t)(n0 + row) * K + kt * 64 + cl * 8, Bs + (size_t)(wave * 4 + i) * 512);
    }
    __syncthreads();

#pragma unroll
    for (int kk = 0; kk < 2; kk++) {
      bf16x8 af[4], bfr[4];
#pragma unroll
      for (int mt = 0; mt < 4; mt++) {
        int row = wr * 64 + mt * 16 + l15;
        int phys = (kk * 4 + quad) ^ (l15 & 7);
        af[mt] = *reinterpret_cast<const bf16x8*>(As + row * 64 + phys * 8);
      }
#pragma unroll
      for (int nt = 0; nt < 4; nt++) {
        int row = wc * 64 + nt * 16 + l15;
        int phys = (kk * 4 + quad) ^ (l15 & 7);
        bfr[nt] = *reinterpret_cast<const bf16x8*>(Bs + row * 64 + phys * 8);
      }
#pragma unroll
      for (int mt = 0; mt < 4; mt++)
#pragma unroll
        for (int nt = 0; nt < 4; nt++) acc[mt][nt] = MFMA_BF16(af[mt], bfr[nt], acc[mt][nt]);
    }
    __syncthreads();
  }

  if constexpr (OUT_MODE == 2) {
    if (third == 2) {
#pragma unroll
      for (int nt = 0; nt < 4; nt++) {
        int col = n0 + wc * 64 + nt * 16 + l15;
#pragma unroll
        for (int mt = 0; mt < 4; mt++) {
          int rowb = m0 + wr * 64 + mt * 16 + quad * 4;
          bf16x4 tv = {(bf16_t)acc[mt][nt][0], (bf16_t)acc[mt][nt][1],
                       (bf16_t)acc[mt][nt][2], (bf16_t)acc[mt][nt][3]};
          *reinterpret_cast<bf16x4*>(Ct + (size_t)col * SEQ + rowb) = tv;
        }
      }
      return;
    }
  }

#pragma unroll
  for (int nt = 0; nt < 4; nt++) {
    int col = n0 + wc * 64 + nt * 16 + l15;
    float bv = 0.f;
    if constexpr (OUT_MODE == 1) bv = bias[col];
#pragma unroll
    for (int mt = 0; mt < 4; mt++) {
      int rowb = m0 + wr * 64 + mt * 16 + quad * 4;
#pragma unroll
      for (int r = 0; r < 4; r++) {
        float vx = acc[mt][nt][r];
        if constexpr (OUT_MODE == 1)
          ((float*)Cp + (size_t)third * cOff)[(size_t)(rowb + r) * ldc + col] = vx + bv;
        else
          ((bf16_t*)Cp + (size_t)third * cOff)[(size_t)(rowb + r) * ldc + col] = (bf16_t)(vx * sc);
      }
    }
  }
}

// ---------------------------------------------------------------------------
// Flash attention — r8-exact version (measured 200 µs; r9's mv double-buffer
// spilled: +32 loop-carried VGPRs -> scratch, 343 µs. This structure is at
// the register ceiling; no added loop-carried state).
// S^T formulation, K=32 PV, software-pipelined, softmax in the QK^T MFMA
// shadow. 4 waves x 32 q (qt=2; r5: qt=1 doubles LDS traffic; r7: 8-wave
// blocks spill).
//  * counted-vmcnt barrier (T4): stage gloads oldest 8, mask loads newest 8
//    (sched_barrier pins order); s_waitcnt vmcnt(8) drains exactly the stages.
//  * loadMask before qkT_sm keeps the 64-MFMA burst unbroken.
// body(t): ctdBarrier -> stage(t+2) -> loadMask(t+1) -> qkT_sm(t+1)[softmax(t)
// in MFMA shadow] -> pv(t). V triple-buffered, K double-buffered: LDS 80 KiB,
// 2 blocks/CU. exp2 = raw v_exp_f32.
// Layout invariants (verified r2): QK^T A-rows permuted so P lands in the
// K=32 B-operand layout; Ks swizzle ^((row&3)|((row&8)>>1)); Vs ^(row&7);
// Q pre-scaled by 1/sqrt(128)*log2e at projection time.
// ---------------------------------------------------------------------------
__global__ __launch_bounds__(256, 2) void attn_kernel(const bf16_t* __restrict__ qb,
                                                      const bf16_t* __restrict__ kb,
                                                      const bf16_t* __restrict__ vtp,
                                                      const float* __restrict__ mask,
                                                      bf16_t* __restrict__ ao) {
  __shared__ bf16_t Ks[2][64 * 128];  // [sk][d], 8-elem chunks, ^((row&3)|((row&8)>>1))
  __shared__ bf16_t Vs[3][128 * 64];  // [d][sk], 8-elem chunks, ^(row&7)
  const int tid = threadIdx.x, lane = tid & 63, w = tid >> 6;
  const int quad = lane >> 4, l15 = lane & 15;
  const int head = blockIdx.x, q0 = blockIdx.y * 128;  // head-major dispatch
  const float LOG2E = 1.4426950408889634f;
  const int NT = SEQ / 64;

  // resident Q fragments (already scaled by 1/sqrt(128)*log2e):
  // lane holds Q[q = qt*16+l15][d = ks*32 + quad*8 + j]
  bf16x8 qf[2][4];
#pragma unroll
  for (int qt = 0; qt < 2; qt++)
#pragma unroll
    for (int ks = 0; ks < 4; ks++)
      qf[qt][ks] = *reinterpret_cast<const bf16x8*>(
          qb + (size_t)(q0 + w * 32 + qt * 16 + l15) * HIDDEN + head * HD + ks * 32 + quad * 8);

  // O^T accumulator: [dt][qt], C-layout col=q=l15, row=d=quad*4+r
  f32x4 O[8][2];
#pragma unroll
  for (int dt = 0; dt < 8; dt++)
#pragma unroll
    for (int qt = 0; qt < 2; qt++) O[dt][qt] = f32x4{0.f, 0.f, 0.f, 0.f};
  float lacc[2] = {0.f, 0.f};

  auto stageK = [&](int kt, int buf) {
#pragma unroll
    for (int i = 0; i < 4; i++) {
      int slot = (w * 4 + i) * 64 + lane;
      int row = slot >> 4, cp = slot & 15;
      int cl = cp ^ ((row & 3) | ((row & 8) >> 1));
      gload16(kb + (size_t)(kt * 64 + row) * HIDDEN + head * HD + cl * 8,
              &Ks[buf][(size_t)(w * 4 + i) * 512]);
    }
  };
  auto stageV = [&](int kt, int buf) {
#pragma unroll
    for (int i = 0; i < 4; i++) {
      int slot = (w * 4 + i) * 64 + lane;
      int row = slot >> 3, cp = slot & 7;
      int cl = cp ^ (row & 7);
      gload16(vtp + (size_t)(head * HD + row) * SEQ + kt * 64 + cl * 8,
              &Vs[buf][(size_t)(w * 4 + i) * 512]);
    }
  };

  // per-lane constants for the permuted A-row reads
  const int sK = (l15 & 3) | (((l15 >> 2) & 1) << 2);  // swizzle key = rowA's bits {0,1,3}
  const int rA0 = ((l15 >> 2) << 3) + (l15 & 3);       // A-row base (kp=0, sub=0)

  f32x4 mv[2][2][2];
  auto loadMask = [&](int kt) {
#pragma unroll
    for (int kp = 0; kp < 2; kp++)
#pragma unroll
      for (int sub = 0; sub < 2; sub++)
#pragma unroll
        for (int qt = 0; qt < 2; qt++)
          mv[kp][sub][qt] = *reinterpret_cast<const f32x4*>(
              mask + (size_t)(q0 + w * 32 + qt * 16 + l15) * SEQ + kt * 64 + kp * 32 + quad * 8 +
              sub * 4);
  };

  f32x4 sacc[2][2][2];   // scores of tile t (consumed by softmax groups)
  bf16x8 pf[2][2];       // [kp][qt]: j=0..3 <- sub0, j=4..7 <- sub1

  // softmax group (kp,sub) of the CURRENT sacc/mv: fma+exp+cvt, pure VALU
  auto smGroup = [&](int kp, int sub) {
#pragma unroll
    for (int qt = 0; qt < 2; qt++) {
      f32x4 e;
#pragma unroll
      for (int r = 0; r < 4; r++)
        e[r] = __builtin_amdgcn_exp2f(sacc[kp][sub][qt][r] + mv[kp][sub][qt][r] * LOG2E);
      lacc[qt] += (e[0] + e[1]) + (e[2] + e[3]);
#pragma unroll
      for (int r = 0; r < 4; r++) pf[kp][qt][sub * 4 + r] = (bf16_t)e[r];
    }
  };

  // plain QK^T into sacc (prologue only)
  auto qkT = [&](int buf) {
#pragma unroll
    for (int kp = 0; kp < 2; kp++)
#pragma unroll
      for (int sub = 0; sub < 2; sub++)
#pragma unroll
        for (int qt = 0; qt < 2; qt++) sacc[kp][sub][qt] = f32x4{0.f, 0.f, 0.f, 0.f};
#pragma unroll
    for (int ks = 0; ks < 4; ks++) {
      int phys = (ks * 4 + quad) ^ sK;
#pragma unroll
      for (int kp = 0; kp < 2; kp++)
#pragma unroll
        for (int sub = 0; sub < 2; sub++) {
          int rowA = kp * 32 + sub * 4 + rA0;
          bf16x8 ak = *reinterpret_cast<const bf16x8*>(&Ks[buf][rowA * 128 + phys * 8]);
#pragma unroll
          for (int qt = 0; qt < 2; qt++)
            sacc[kp][sub][qt] = MFMA_BF16(ak, qf[qt][ks], sacc[kp][sub][qt]);
        }
    }
  };

  // QK^T(t+1) into fresh regs, softmax(t) interleaved per ks-step; publish.
  auto qkT_sm = [&](int buf) {
    f32x4 ns[2][2][2];
#pragma unroll
    for (int kp = 0; kp < 2; kp++)
#pragma unroll
      for (int sub = 0; sub < 2; sub++)
#pragma unroll
        for (int qt = 0; qt < 2; qt++) ns[kp][sub][qt] = f32x4{0.f, 0.f, 0.f, 0.f};
#pragma unroll
    for (int ks = 0; ks < 4; ks++) {
      int phys = (ks * 4 + quad) ^ sK;
#pragma unroll
      for (int kp = 0; kp < 2; kp++)
#pragma unroll
        for (int sub = 0; sub < 2; sub++) {
          int rowA = kp * 32 + sub * 4 + rA0;
          bf16x8 ak = *reinterpret_cast<const bf16x8*>(&Ks[buf][rowA * 128 + phys * 8]);
#pragma unroll
          for (int qt = 0; qt < 2; qt++)
            ns[kp][sub][qt] = MFMA_BF16(ak, qf[qt][ks], ns[kp][sub][qt]);
        }
      smGroup(ks >> 1, ks & 1);  // VALU of tile t hides under the MFMA burst
    }
#pragma unroll
    for (int kp = 0; kp < 2; kp++)
#pragma unroll
      for (int sub = 0; sub < 2; sub++)
#pragma unroll
        for (int qt = 0; qt < 2; qt++) sacc[kp][sub][qt] = ns[kp][sub][qt];
  };

  auto pv = [&](const bf16_t* Vb) {
#pragma unroll
    for (int kp = 0; kp < 2; kp++)
#pragma unroll
      for (int dt = 0; dt < 8; dt++) {
        int row = dt * 16 + l15;
        int phys = (kp * 4 + quad) ^ (l15 & 7);
        bf16x8 av = *reinterpret_cast<const bf16x8*>(&Vb[row * 64 + phys * 8]);
#pragma unroll
        for (int qt = 0; qt < 2; qt++) O[dt][qt] = MFMA_BF16(av, pf[kp][qt], O[dt][qt]);
      }
  };

  // prologue: tiles 0 and 1 staged; sacc(0), mv(0) ready
  stageK(0, 0);
  stageV(0, 0);
  stageK(1, 1);
  stageV(1, 1);
  loadMask(0);
  __syncthreads();  // full drain once (prologue only)
  qkT(0);           // sacc(0)

  int vb_pv = 0;  // Vs buffer holding V(t)
  int vb_st = 2;  // Vs buffer receiving V(t+2)
  for (int t = 0; t < NT - 1; ++t) {
    // counted-vmcnt barrier: drain my 8 stage gloads (oldest) + my ds_reads;
    // leave the 8 mask loads (newest) in flight across the barrier.
    asm volatile("s_waitcnt vmcnt(8) lgkmcnt(0)" ::: "memory");
    __builtin_amdgcn_s_barrier();
    __builtin_amdgcn_sched_barrier(0);  // nothing hoists above the barrier
    stageK(t + 2, t & 1); // overwrites K(t) buffer — reads drained above
    stageV(t + 2, vb_st); // overwrites V(t-1) buffer — reads drained above
    __builtin_amdgcn_sched_barrier(0);  // masks must issue AFTER stages (vmcnt age)
    loadMask(t + 1);      // in flight until smGroups in iter t+1
    __builtin_amdgcn_s_setprio(1);
    qkT_sm((t + 1) & 1);  // sacc(t+1) MFMAs + softmax(t) VALU interleaved
    pv(&Vs[vb_pv][0]);    // O += V(t)·P(t) — one unbroken 64-MFMA burst
    __builtin_amdgcn_s_setprio(0);
    vb_pv = vb_pv == 2 ? 0 : vb_pv + 1;
    vb_st = vb_st == 2 ? 0 : vb_st + 1;
  }
  // tail: t = NT-1 (V(NT-1) staged at t=NT-3, drained at the last barrier)
  smGroup(0, 0);
  smGroup(0, 1);
  smGroup(1, 0);
  smGroup(1, 1);
  pv(&Vs[vb_pv][0]);

  // epilogue: reduce l across quads (lanes l15, +16, +32, +48 share q), write O
#pragma unroll
  for (int qt = 0; qt < 2; qt++) {
    float l = lacc[qt];
    l += __shfl_xor(l, 16, 64);
    l += __shfl_xor(l, 32, 64);
    lacc[qt] = 1.f / l;
  }
#pragma unroll
  for (int dt = 0; dt < 8; dt++)
#pragma unroll
    for (int qt = 0; qt < 2; qt++) {
      int q = q0 + w * 32 + qt * 16 + l15;
      int d = head * HD + dt * 16 + quad * 4;
      f32x4 o = O[dt][qt];
      bf16x4 ov = {(bf16_t)(o[0] * lacc[qt]), (bf16_t)(o[1] * lacc[qt]),
                   (bf16_t)(o[2] * lacc[qt]), (bf16_t)(o[3] * lacc[qt])};
      *reinterpret_cast<bf16x4*>(ao + (size_t)q * HIDDEN + d) = ov;
    }
}

// ---------------------------------------------------------------------------
extern "C" void kernel_launch(void* const* d_in, const int* in_sizes, int n_in,
                              void* d_out, int out_size, void* d_ws, size_t ws_size,
                              hipStream_t stream) {
  (void)in_sizes; (void)n_in; (void)out_size; (void)ws_size;
  const float* x = (const float*)d_in[0];
  const float* mask = (const float*)d_in[1];
  const float* qV = (const float*)d_in[2];
  const float* qU = (const float*)d_in[3];
  const float* kV = (const float*)d_in[4];
  const float* kU = (const float*)d_in[5];
  const float* vV = (const float*)d_in[6];
  const float* vU = (const float*)d_in[7];
  const float* oW = (const float*)d_in[8];
  const float* ob = (const float*)d_in[9];
  float* out = (float*)d_out;

  char* ws = (char*)d_ws;
  const size_t MB = 1ull << 20;
  bf16_t* xb  = (bf16_t*)(ws);            // 16 MiB [4096][2048]; reused as ao
  bf16_t* tmp = (bf16_t*)(ws + 16 * MB);  // 24 MiB [4096][3072]
  bf16_t* qkv = (bf16_t*)(ws + 40 * MB);  // 48 MiB: q, k sections + vt in v-section
  bf16_t* qVb = (bf16_t*)(ws + 88 * MB);
  bf16_t* qUb = (bf16_t*)(ws + 92 * MB);
  bf16_t* kVb = (bf16_t*)(ws + 96 * MB);
  bf16_t* kUb = (bf16_t*)(ws + 100 * MB);
  bf16_t* vVb = (bf16_t*)(ws + 104 * MB);
  bf16_t* vUb = (bf16_t*)(ws + 108 * MB);
  bf16_t* oWb = (bf16_t*)(ws + 112 * MB);  // ends at 120 MiB
  bf16_t* vt = qkv + 2 * (size_t)SEQ * HIDDEN;  // [2048][4096], written transposed by gemm3<2>

  // 1/sqrt(HD) * log2(e), folded into Q at the U-projection epilogue
  const float kQScale = 0.088388347648318447f * 1.4426950408889634f;

  CastArgs ca;
  ca.seg[0] = {x, xb, SEQ * HIDDEN / 4};
  ca.seg[1] = {qV, qVb, RANK * HIDDEN / 4};
  ca.seg[2] = {qU, qUb, HIDDEN * RANK / 4};
  ca.seg[3] = {kV, kVb, RANK * HIDDEN / 4};
  ca.seg[4] = {kU, kUb, HIDDEN * RANK / 4};
  ca.seg[5] = {vV, vVb, RANK * HIDDEN / 4};
  ca.seg[6] = {vU, vUb, HIDDEN * RANK / 4};
  ca.seg[7] = {oW, oWb, HIDDEN * HIDDEN / 4};
  cast_bf16_kernel<<<2048, 256, 0, stream>>>(ca);

  // fused V-projections: tmp[4096][3072] = xb @ {qV,kV,vV}^T
  gemm3<0><<<dim3(24, 32), 256, 0, stream>>>(xb, HIDDEN, 0, qVb, kVb, vVb, RANK, HIDDEN,
                                             tmp, 3 * RANK, (size_t)RANK, nullptr, 1.f, nullptr);
  // fused U-projections: q,k -> qkv sections (q pre-scaled); v -> vt TRANSPOSED
  gemm3<2><<<dim3(48, 32), 256, 0, stream>>>(tmp, 3 * RANK, RANK, qUb, kUb, vUb, HIDDEN, RANK,
                                             qkv, HIDDEN, (size_t)SEQ * HIDDEN, nullptr,
                                             kQScale, vt);
  // attention -> ao (= xb region); head-major grid, 4 waves x 32 q
  attn_kernel<<<dim3(HEADS, SEQ / 128), 256, 0, stream>>>(qkv, qkv + (size_t)SEQ * HIDDEN, vt,
                                                          mask, xb);
  // out = ao @ oW^T + b (fp32)
  gemm3<1><<<dim3(16, 32), 256, 0, stream>>>(xb, HIDDEN, 0, oWb, oWb, oWb, HIDDEN, HIDDEN,
                                             out, HIDDEN, 0, ob, 1.f, nullptr);
}